// Round 5
// baseline (210.437 us; speedup 1.0000x reference)
//
#include <hip/hip_runtime.h>
#include <stdint.h>

// Problem constants (B=8, T=2048, D=256, K=8192)
#define M_TOK 16384
#define DIM   256
#define KCB   8192
#define NGRP  8                    // N-groups (blocks in y)
#define GRP   1024                 // codes per group
#define SHIFT 512.0f               // positivity shift for score packing
#define INV_N (1.0f / 4194304.0f)  // 1/(B*T*D)

typedef __attribute__((ext_vector_type(4))) float f32x4;
typedef __attribute__((ext_vector_type(8))) __bf16 bf16x8;

static __device__ __forceinline__ unsigned short f2bf(float f) {
    uint32_t x = __float_as_uint(f);
    uint32_t r = (x + 0x7fffu + ((x >> 16) & 1u)) >> 16;   // RNE
    return (unsigned short)r;
}

// 16-byte global load, bit-cast to a bf16 MFMA fragment.
static __device__ __forceinline__ bf16x8 gload8(const unsigned short* p) {
    union { uint4 u; bf16x8 b; } cv;
    cv.u = *(const uint4*)p;
    return cv.b;
}

// ---------------------------------------------------------------- kernel 1
// Merged prep: blocks [0,4096): xs -> bf16. Blocks [4096,6144): codebook ->
// NEGATED bf16 (so MFMA accumulates -x.c) and chalf = 0.5*||c||^2 + SHIFT.
__global__ void k_prep(const float4* __restrict__ xs4,
                       ushort4* __restrict__ xb4,
                       const float4* __restrict__ cb4,
                       ushort4* __restrict__ cbbn4,
                       float* __restrict__ chalf) {
    int b = blockIdx.x;
    if (b < 4096) {
        int i = b * 256 + threadIdx.x;
        float4 v = xs4[i];
        ushort4 o;
        o.x = f2bf(v.x); o.y = f2bf(v.y); o.z = f2bf(v.z); o.w = f2bf(v.w);
        xb4[i] = o;
    } else {
        b -= 4096;
        int row  = b * 4 + (threadIdx.x >> 6);
        int lane = threadIdx.x & 63;
        int idx  = row * 64 + lane;
        float4 v = cb4[idx];
        ushort4 o;                                   // store -c in bf16
        o.x = f2bf(-v.x); o.y = f2bf(-v.y); o.z = f2bf(-v.z); o.w = f2bf(-v.w);
        cbbn4[idx] = o;
        float s = v.x * v.x + v.y * v.y + v.z * v.z + v.w * v.w;
        #pragma unroll
        for (int off = 32; off; off >>= 1) s += __shfl_xor(s, off);
        if (lane == 0) chalf[row] = 0.5f * s + SHIFT;
    }
}

// ---------------------------------------------------------------- kernel 2
// A-in-registers MFMA GEMM + argmin. grid (128, 8), 256 thr = 4 waves.
// Wave = 64 rows (rh=w>>1) x 64 codes (ch=w&1) per 128-tile; rt=4, ct=4.
// A frags (4x8, 128 VGPR) loaded ONCE in MFMA A-layout; B frags loaded
// global->VGPR per K-step (L2-resident codebook; twin waves share lines via
// L1). NO LDS / NO barriers in the main loop -> no vmcnt(0) drains, no bank
// conflicts (round-4: LDS pipe was 2.5x the MFMA roof; this removes it).
// acc init = 0.5||c||^2+SHIFT, B = -c  =>  acc_final = positive score.
__global__ __launch_bounds__(256, 2) void k_gemm_argmin(
    const unsigned short* __restrict__ xb,     // [M_TOK][DIM] bf16
    const unsigned short* __restrict__ cbbn,   // [KCB][DIM]  bf16 of -c
    const float* __restrict__ chalf,           // [KCB] = 0.5||c||^2+SHIFT
    uint32_t* __restrict__ pkey)               // [M_TOK][NGRP]
{
    __shared__ uint32_t skey[128][2];

    const int tid  = threadIdx.x;
    const int w    = tid >> 6;
    const int l    = tid & 63;
    const int lrow = l & 15;          // fragment row/col index
    const int quad = l >> 4;          // 0..3 (k-segment / acc row group)
    const int ch   = w & 1;           // col-half (codes)
    const int rh   = w >> 1;          // row-half (tokens)
    const int m0 = blockIdx.x * 128;
    const int g  = blockIdx.y;

    // per-lane base pointers (A-layout: row=lrow, k-seg=quad)
    const unsigned short* Ab = xb   + (size_t)(m0 + rh * 64 + lrow) * DIM + quad * 8;
    const unsigned short* Bb = cbbn + (size_t)(g * GRP + ch * 64 + lrow) * DIM + quad * 8;
    const float*          cp = chalf + g * GRP + ch * 64 + lrow;

    // ---- load the wave's entire A panel into registers (64 rows x 256 K)
    bf16x8 afr[4][8];
    #pragma unroll
    for (int rt = 0; rt < 4; rt++)
        #pragma unroll
        for (int kt = 0; kt < 8; kt++)
            afr[rt][kt] = gload8(Ab + rt * 16 * DIM + kt * 32);

    uint32_t best[4][4];
    #pragma unroll
    for (int rt = 0; rt < 4; rt++)
        #pragma unroll
        for (int rg = 0; rg < 4; rg++) best[rt][rg] = 0xFFFFFFFFu;

    #pragma unroll
    for (int t = 0; t < 8; t++) {
        // acc init from 0.5||c||^2 + SHIFT (L1-hot 4 KB table)
        f32x4 acc[4][4];
        #pragma unroll
        for (int ct = 0; ct < 4; ct++) {
            float cs = cp[t * 128 + ct * 16];
            #pragma unroll
            for (int rt = 0; rt < 4; rt++) {
                f32x4 c4 = {cs, cs, cs, cs};
                acc[rt][ct] = c4;
            }
        }
        #pragma unroll
        for (int kt = 0; kt < 8; kt++) {
            bf16x8 bfr[4];
            #pragma unroll
            for (int ct = 0; ct < 4; ct++)
                bfr[ct] = gload8(Bb + t * 128 * DIM + ct * 16 * DIM + kt * 32);
            #pragma unroll
            for (int rt = 0; rt < 4; rt++)
                #pragma unroll
                for (int ct = 0; ct < 4; ct++)
                    acc[rt][ct] = __builtin_amdgcn_mfma_f32_16x16x32_bf16(
                        afr[rt][kt], bfr[ct], acc[rt][ct], 0, 0, 0);
        }
        // fold tile scores into packed keys: (score_bits & ~1023) | local_id
        #pragma unroll
        for (int ct = 0; ct < 4; ct++) {
            uint32_t idl = (uint32_t)(t * 128 + ch * 64 + ct * 16 + lrow);
            #pragma unroll
            for (int rt = 0; rt < 4; rt++)
                #pragma unroll
                for (int rg = 0; rg < 4; rg++) {
                    uint32_t key =
                        (__float_as_uint(acc[rt][ct][rg]) & 0xFFFFFC00u) | idl;
                    if (key < best[rt][rg]) best[rt][rg] = key;
                }
        }
    }

    // min across the 16 lanes sharing a quad (same rows, different codes)
    #pragma unroll
    for (int off = 1; off < 16; off <<= 1)
        #pragma unroll
        for (int rt = 0; rt < 4; rt++)
            #pragma unroll
            for (int rg = 0; rg < 4; rg++) {
                uint32_t o = __shfl_xor(best[rt][rg], off);
                if (o < best[rt][rg]) best[rt][rg] = o;
            }
    if (lrow == 0) {
        #pragma unroll
        for (int rt = 0; rt < 4; rt++)
            #pragma unroll
            for (int rg = 0; rg < 4; rg++)
                skey[rh * 64 + rt * 16 + quad * 4 + rg][ch] = best[rt][rg];
    }
    __syncthreads();
    if (tid < 128) {
        uint32_t k0 = skey[tid][0], k1 = skey[tid][1];
        pkey[(size_t)(m0 + tid) * NGRP + g] = k0 < k1 ? k0 : k1;
    }
}

// ---------------------------------------------------------------- kernel 3
// Per row: min over 8 group keys -> final code; exact fp32 ||x-c||^2;
// per-block LDS reduce -> partial[blockIdx]. No global atomics.
__global__ void k_finalize(const uint32_t* __restrict__ pkey,
                           const float4* __restrict__ xs4,
                           const float4* __restrict__ cb4,
                           float* __restrict__ partial) {
    __shared__ float sblk[4];
    int w   = threadIdx.x >> 6;
    int row = blockIdx.x * 4 + w;
    int l   = threadIdx.x & 63;
    uint32_t k = 0xFFFFFFFFu;
    int g = 0;
    if (l < 8) { k = pkey[(size_t)row * NGRP + l]; g = l; }
    #pragma unroll
    for (int off = 1; off < 8; off <<= 1) {
        uint32_t ok = __shfl_xor(k, off);
        int      og = __shfl_xor(g, off);
        if (ok < k) { k = ok; g = og; }
    }
    k = __shfl(k, 0);
    g = __shfl(g, 0);
    int code = g * GRP + (int)(k & 1023u);
    float4 x = xs4[(size_t)row * 64 + l];
    float4 c = cb4[(size_t)code * 64 + l];
    float dx = x.x - c.x, dy = x.y - c.y, dz = x.z - c.z, dw = x.w - c.w;
    float s = dx * dx + dy * dy + dz * dz + dw * dw;
    #pragma unroll
    for (int off = 32; off; off >>= 1) s += __shfl_xor(s, off);
    if (l == 0) sblk[w] = s;
    __syncthreads();
    if (threadIdx.x == 0)
        partial[blockIdx.x] = sblk[0] + sblk[1] + sblk[2] + sblk[3];
}

// ---------------------------------------------------------------- kernel 4
__global__ void k_write(const float* __restrict__ partial,
                        float* __restrict__ out) {
    __shared__ float swv[16];
    int tid = threadIdx.x;                    // 1024 threads = 16 waves
    float s = partial[tid] + partial[tid + 1024] +
              partial[tid + 2048] + partial[tid + 3072];
    #pragma unroll
    for (int off = 32; off; off >>= 1) s += __shfl_xor(s, off);
    if ((tid & 63) == 0) swv[tid >> 6] = s;
    __syncthreads();
    if (tid == 0) {
        float t = 0.0f;
        #pragma unroll
        for (int i = 0; i < 16; i++) t += swv[i];
        float commit = t * INV_N;
        out[0] = 0.25f * commit;   // loss
        out[1] = commit;           // commit_loss
    }
}

extern "C" void kernel_launch(void* const* d_in, const int* in_sizes, int n_in,
                              void* d_out, int out_size, void* d_ws, size_t ws_size,
                              hipStream_t stream) {
    const float* xs = (const float*)d_in[0];
    // d_in[1] = ilens (int64, all == T) -> slice is a no-op, unused
    const float* cb = (const float*)d_in[2];

    char* ws = (char*)d_ws;
    unsigned short* xb      = (unsigned short*)(ws + 256);              // 8 MiB
    unsigned short* cbbn    = (unsigned short*)(ws + 256 + 8388608);    // 4 MiB
    float*          chalf   = (float*)(ws + 256 + 12582912);            // 32 KiB
    uint32_t*       pkey    = (uint32_t*)(ws + 256 + 12615680);         // 512 KiB
    float*          partial = (float*)(ws + 256 + 13139968);            // 16 KiB

    k_prep<<<6144, 256, 0, stream>>>((const float4*)xs, (ushort4*)xb,
                                     (const float4*)cb, (ushort4*)cbbn, chalf);
    dim3 g(M_TOK / 128, NGRP);
    k_gemm_argmin<<<g, 256, 0, stream>>>(xb, cbbn, chalf, pkey);
    k_finalize<<<4096, 256, 0, stream>>>(pkey, (const float4*)xs,
                                         (const float4*)cb, partial);
    k_write<<<1, 1024, 0, stream>>>(partial, (float*)d_out);
}

// Round 6
// 157.833 us; speedup vs baseline: 1.3333x; 1.3333x over previous
//
#include <hip/hip_runtime.h>
#include <stdint.h>

// Problem constants (B=8, T=2048, D=256, K=8192)
#define M_TOK 16384
#define DIM   256
#define KCB   8192
#define NGRP  8                    // N-groups (blocks in y)
#define GRP   1024                 // codes per group
#define NCHK  32                   // 16B k-chunks per row (256*2B/16B)
#define SHIFT 512.0f               // positivity shift for score packing
#define INV_N (1.0f / 4194304.0f)  // 1/(B*T*D)

typedef __attribute__((ext_vector_type(4))) float f32x4;
typedef __attribute__((ext_vector_type(8))) __bf16 bf16x8;

static __device__ __forceinline__ unsigned short f2bf(float f) {
    uint32_t x = __float_as_uint(f);
    uint32_t r = (x + 0x7fffu + ((x >> 16) & 1u)) >> 16;   // RNE
    return (unsigned short)r;
}

// pack 8 floats -> bf16x8 (RNE)
static __device__ __forceinline__ bf16x8 cvt8(float4 a, float4 b) {
    union { unsigned short u[8]; bf16x8 v; } r;
    r.u[0] = f2bf(a.x); r.u[1] = f2bf(a.y); r.u[2] = f2bf(a.z); r.u[3] = f2bf(a.w);
    r.u[4] = f2bf(b.x); r.u[5] = f2bf(b.y); r.u[6] = f2bf(b.z); r.u[7] = f2bf(b.w);
    return r.v;
}

// Async global->LDS DMA, 16 B/lane; LDS dest = wave-uniform base + lane*16.
static __device__ __forceinline__ void lds_cp16(const void* g, void* l) {
    __builtin_amdgcn_global_load_lds(
        (const __attribute__((address_space(1))) void*)g,
        (__attribute__((address_space(3))) void*)l, 16, 0, 0);
}

// ---------------------------------------------------------------- kernel 1
// Codebook prep: cbt[chunk][code][8] = bf16 of -c, k-chunk-major (so GEMM's
// LDS staging reads 1KB-contiguous rows); chalf = 0.5||c||^2 + SHIFT.
// Block = 64 codes; wave w handles k-chunks [8w, 8w+8); lane = code.
__global__ void k_prep(const float* __restrict__ cb,
                       unsigned short* __restrict__ cbt,
                       float* __restrict__ chalf) {
    __shared__ float part[4][64];
    const int w  = threadIdx.x >> 6;
    const int l  = threadIdx.x & 63;
    const int c0 = blockIdx.x * 64;
    const float* row = cb + (size_t)(c0 + l) * DIM;
    float s = 0.0f;
    #pragma unroll
    for (int j = 0; j < 8; j++) {
        int cr = w * 8 + j;
        float4 f0 = *(const float4*)(row + cr * 8);
        float4 f1 = *(const float4*)(row + cr * 8 + 4);
        s += f0.x * f0.x + f0.y * f0.y + f0.z * f0.z + f0.w * f0.w +
             f1.x * f1.x + f1.y * f1.y + f1.z * f1.z + f1.w * f1.w;
        union { unsigned short u[8]; uint4 q; } r;
        r.u[0] = f2bf(-f0.x); r.u[1] = f2bf(-f0.y);
        r.u[2] = f2bf(-f0.z); r.u[3] = f2bf(-f0.w);
        r.u[4] = f2bf(-f1.x); r.u[5] = f2bf(-f1.y);
        r.u[6] = f2bf(-f1.z); r.u[7] = f2bf(-f1.w);
        *(uint4*)(cbt + ((size_t)cr * KCB + c0 + l) * 8) = r.q;   // 1KB/wave coalesced
    }
    part[w][l] = s;
    __syncthreads();
    if (w == 0) {
        float t = part[0][l] + part[1][l] + part[2][l] + part[3][l];
        chalf[c0 + l] = 0.5f * t + SHIFT;
    }
}

// ---------------------------------------------------------------- kernel 2
// Hybrid GEMM+argmin: A panel resident in VGPRs (loaded fp32, converted to
// bf16 in-register -> remat is expensive, allocator keeps it), B streamed
// through LDS one 128-code tile at a time (64 KB, k-chunk-major: staging is
// 1KB-contiguous, frag ds_read_b128s are 256B-contiguous -> conflict-free).
// grid (128, 8), 4 waves; wave = 64 rows (rh) x 64 codes (ch); rt=4, ct=4.
// acc init = 0.5||c||^2+SHIFT, B = -c  =>  acc_final = positive score.
__global__ __launch_bounds__(256, 2) void k_gemm_argmin(
    const float* __restrict__ xs,              // [M_TOK][DIM] fp32
    const unsigned short* __restrict__ cbt,    // [NCHK][KCB][8] bf16 of -c
    const float* __restrict__ chalf,           // [KCB] = 0.5||c||^2+SHIFT
    uint32_t* __restrict__ pkey)               // [M_TOK][NGRP]
{
    __shared__ __align__(16) unsigned short Bs[NCHK][128][8];   // 64 KB
    __shared__ float schalf[GRP];
    __shared__ uint32_t skey[128][2];

    const int tid  = threadIdx.x;
    const int w    = tid >> 6;
    const int l    = tid & 63;
    const int lrow = l & 15;
    const int quad = l >> 4;
    const int rh   = w >> 1;
    const int ch   = w & 1;
    const int m0 = blockIdx.x * 128;
    const int g  = blockIdx.y;

    // chalf slice (4 KB) -> LDS
    *(float4*)&schalf[tid * 4] = ((const float4*)(chalf + g * GRP))[tid];

    // ---- A panel: 64 rows x 256 k, fp32 -> bf16 frags (128 VGPRs)
    bf16x8 afr[4][8];
    {
        const float* ap = xs + (size_t)(m0 + rh * 64 + lrow) * DIM + quad * 8;
        #pragma unroll
        for (int rt = 0; rt < 4; rt++)
            #pragma unroll
            for (int kt = 0; kt < 8; kt++) {
                const float* p = ap + rt * 16 * DIM + kt * 32;
                float4 f0 = *(const float4*)p;
                float4 f1 = *(const float4*)(p + 4);
                afr[rt][kt] = cvt8(f0, f1);
            }
    }

    uint32_t best[4][4];
    #pragma unroll
    for (int rt = 0; rt < 4; rt++)
        #pragma unroll
        for (int rg = 0; rg < 4; rg++) best[rt][rg] = 0xFFFFFFFFu;

    // staging source: wave w supplies chunk rows [8w, 8w+8), lane = code
    const unsigned short* bsrc = cbt + ((size_t)(w * 8) * KCB + g * GRP + l) * 8;

    #pragma unroll 1
    for (int t = 0; t < 8; t++) {
        __syncthreads();                       // previous tile's readers done
        #pragma unroll
        for (int j = 0; j < 8; j++)
            #pragma unroll
            for (int h = 0; h < 2; h++)
                lds_cp16(bsrc + ((size_t)j * KCB + t * 128 + h * 64) * 8,
                         &Bs[w * 8 + j][h * 64][0]);
        __syncthreads();                       // Bs valid (drains DMA)

        f32x4 acc[4][4];
        #pragma unroll
        for (int ct = 0; ct < 4; ct++) {
            float cs = schalf[t * 128 + ch * 64 + ct * 16 + lrow];
            #pragma unroll
            for (int rt = 0; rt < 4; rt++) {
                f32x4 c4 = {cs, cs, cs, cs};
                acc[rt][ct] = c4;
            }
        }
        #pragma unroll
        for (int bk = 0; bk < 8; bk++) {
            bf16x8 bfr[4];
            #pragma unroll
            for (int ct = 0; ct < 4; ct++)
                bfr[ct] = *(const bf16x8*)&Bs[bk * 4 + quad]
                                             [ch * 64 + ct * 16 + lrow][0];
            #pragma unroll
            for (int rt = 0; rt < 4; rt++)
                #pragma unroll
                for (int ct = 0; ct < 4; ct++)
                    acc[rt][ct] = __builtin_amdgcn_mfma_f32_16x16x32_bf16(
                        afr[rt][bk], bfr[ct], acc[rt][ct], 0, 0, 0);
        }
        // fold scores into packed keys: (score_bits & ~1023) | group-local id
        #pragma unroll
        for (int ct = 0; ct < 4; ct++) {
            uint32_t idl = (uint32_t)(t * 128 + ch * 64 + ct * 16 + lrow);
            #pragma unroll
            for (int rt = 0; rt < 4; rt++)
                #pragma unroll
                for (int rg = 0; rg < 4; rg++) {
                    uint32_t key =
                        (__float_as_uint(acc[rt][ct][rg]) & 0xFFFFFC00u) | idl;
                    if (key < best[rt][rg]) best[rt][rg] = key;
                }
        }
    }

    // min across the 16 lanes sharing a quad (same rows, different codes)
    #pragma unroll
    for (int off = 1; off < 16; off <<= 1)
        #pragma unroll
        for (int rt = 0; rt < 4; rt++)
            #pragma unroll
            for (int rg = 0; rg < 4; rg++) {
                uint32_t o = __shfl_xor(best[rt][rg], off);
                if (o < best[rt][rg]) best[rt][rg] = o;
            }
    if (lrow == 0) {
        #pragma unroll
        for (int rt = 0; rt < 4; rt++)
            #pragma unroll
            for (int rg = 0; rg < 4; rg++)
                skey[rh * 64 + rt * 16 + quad * 4 + rg][ch] = best[rt][rg];
    }
    __syncthreads();
    if (tid < 128) {
        uint32_t k0 = skey[tid][0], k1 = skey[tid][1];
        pkey[(size_t)(m0 + tid) * NGRP + g] = k0 < k1 ? k0 : k1;
    }
}

// ---------------------------------------------------------------- kernel 3
// Per row: min over 8 group keys -> final code; exact fp32 ||x-c||^2;
// per-block LDS reduce -> partial[blockIdx]. No global atomics.
__global__ void k_finalize(const uint32_t* __restrict__ pkey,
                           const float4* __restrict__ xs4,
                           const float4* __restrict__ cb4,
                           float* __restrict__ partial) {
    __shared__ float sblk[4];
    int w   = threadIdx.x >> 6;
    int row = blockIdx.x * 4 + w;
    int l   = threadIdx.x & 63;
    uint32_t k = 0xFFFFFFFFu;
    int g = 0;
    if (l < 8) { k = pkey[(size_t)row * NGRP + l]; g = l; }
    #pragma unroll
    for (int off = 1; off < 8; off <<= 1) {
        uint32_t ok = __shfl_xor(k, off);
        int      og = __shfl_xor(g, off);
        if (ok < k) { k = ok; g = og; }
    }
    k = __shfl(k, 0);
    g = __shfl(g, 0);
    int code = g * GRP + (int)(k & 1023u);
    float4 x = xs4[(size_t)row * 64 + l];
    float4 c = cb4[(size_t)code * 64 + l];
    float dx = x.x - c.x, dy = x.y - c.y, dz = x.z - c.z, dw = x.w - c.w;
    float s = dx * dx + dy * dy + dz * dz + dw * dw;
    #pragma unroll
    for (int off = 32; off; off >>= 1) s += __shfl_xor(s, off);
    if (l == 0) sblk[w] = s;
    __syncthreads();
    if (threadIdx.x == 0)
        partial[blockIdx.x] = sblk[0] + sblk[1] + sblk[2] + sblk[3];
}

// ---------------------------------------------------------------- kernel 4
__global__ void k_write(const float* __restrict__ partial,
                        float* __restrict__ out) {
    __shared__ float swv[16];
    int tid = threadIdx.x;                    // 1024 threads = 16 waves
    float s = partial[tid] + partial[tid + 1024] +
              partial[tid + 2048] + partial[tid + 3072];
    #pragma unroll
    for (int off = 32; off; off >>= 1) s += __shfl_xor(s, off);
    if ((tid & 63) == 0) swv[tid >> 6] = s;
    __syncthreads();
    if (tid == 0) {
        float t = 0.0f;
        #pragma unroll
        for (int i = 0; i < 16; i++) t += swv[i];
        float commit = t * INV_N;
        out[0] = 0.25f * commit;   // loss
        out[1] = commit;           // commit_loss
    }
}

extern "C" void kernel_launch(void* const* d_in, const int* in_sizes, int n_in,
                              void* d_out, int out_size, void* d_ws, size_t ws_size,
                              hipStream_t stream) {
    const float* xs = (const float*)d_in[0];
    // d_in[1] = ilens (int64, all == T) -> slice is a no-op, unused
    const float* cb = (const float*)d_in[2];

    char* ws = (char*)d_ws;
    unsigned short* cbt     = (unsigned short*)(ws + 256);          // 4 MiB
    float*          chalf   = (float*)(ws + 256 + 4194304);         // 32 KiB
    uint32_t*       pkey    = (uint32_t*)(ws + 256 + 4227072);      // 512 KiB
    float*          partial = (float*)(ws + 256 + 4751360);         // 16 KiB

    k_prep<<<128, 256, 0, stream>>>(cb, cbt, chalf);
    dim3 g(M_TOK / 128, NGRP);
    k_gemm_argmin<<<g, 256, 0, stream>>>(xs, cbt, chalf, pkey);
    k_finalize<<<4096, 256, 0, stream>>>(pkey, (const float4*)xs,
                                         (const float4*)cb, partial);
    k_write<<<1, 1024, 0, stream>>>(partial, (float*)d_out);
}

// Round 7
// 143.899 us; speedup vs baseline: 1.4624x; 1.0968x over previous
//
#include <hip/hip_runtime.h>
#include <stdint.h>

// Problem constants (B=8, T=2048, D=256, K=8192)
#define M_TOK 16384
#define DIM   256
#define KCB   8192
#define NGRP  8                    // N-groups (blocks in y)
#define GRP   1024                 // codes per group
#define NCHK  32                   // 16B k-chunks per row (256*2B/16B)
#define NT    16                   // 64-code tiles per group
#define SHIFT 512.0f               // positivity shift for score packing
#define INV_N (1.0f / 4194304.0f)  // 1/(B*T*D)

typedef __attribute__((ext_vector_type(4))) float f32x4;
typedef __attribute__((ext_vector_type(8))) __bf16 bf16x8;

static __device__ __forceinline__ unsigned short f2bf(float f) {
    uint32_t x = __float_as_uint(f);
    uint32_t r = (x + 0x7fffu + ((x >> 16) & 1u)) >> 16;   // RNE
    return (unsigned short)r;
}

// pack 8 floats -> bf16x8 (RNE)
static __device__ __forceinline__ bf16x8 cvt8(float4 a, float4 b) {
    union { unsigned short u[8]; bf16x8 v; } r;
    r.u[0] = f2bf(a.x); r.u[1] = f2bf(a.y); r.u[2] = f2bf(a.z); r.u[3] = f2bf(a.w);
    r.u[4] = f2bf(b.x); r.u[5] = f2bf(b.y); r.u[6] = f2bf(b.z); r.u[7] = f2bf(b.w);
    return r.v;
}

// Async global->LDS DMA, 16 B/lane; LDS dest = wave-uniform base + lane*16.
static __device__ __forceinline__ void lds_cp16(const void* g, void* l) {
    __builtin_amdgcn_global_load_lds(
        (const __attribute__((address_space(1))) void*)g,
        (__attribute__((address_space(3))) void*)l, 16, 0, 0);
}

// ---------------------------------------------------------------- kernel 1
// Codebook prep: cbt[chunk][code][8] = bf16 of -c, k-chunk-major (so GEMM's
// LDS staging reads are lane-contiguous); chalf = 0.5||c||^2 + SHIFT.
// Block = 64 codes; wave w handles k-chunks [8w, 8w+8); lane = code.
__global__ void k_prep(const float* __restrict__ cb,
                       unsigned short* __restrict__ cbt,
                       float* __restrict__ chalf) {
    __shared__ float part[4][64];
    const int w  = threadIdx.x >> 6;
    const int l  = threadIdx.x & 63;
    const int c0 = blockIdx.x * 64;
    const float* row = cb + (size_t)(c0 + l) * DIM;
    float s = 0.0f;
    #pragma unroll
    for (int j = 0; j < 8; j++) {
        int cr = w * 8 + j;
        float4 f0 = *(const float4*)(row + cr * 8);
        float4 f1 = *(const float4*)(row + cr * 8 + 4);
        s += f0.x * f0.x + f0.y * f0.y + f0.z * f0.z + f0.w * f0.w +
             f1.x * f1.x + f1.y * f1.y + f1.z * f1.z + f1.w * f1.w;
        union { unsigned short u[8]; uint4 q; } r;
        r.u[0] = f2bf(-f0.x); r.u[1] = f2bf(-f0.y);
        r.u[2] = f2bf(-f0.z); r.u[3] = f2bf(-f0.w);
        r.u[4] = f2bf(-f1.x); r.u[5] = f2bf(-f1.y);
        r.u[6] = f2bf(-f1.z); r.u[7] = f2bf(-f1.w);
        *(uint4*)(cbt + ((size_t)cr * KCB + c0 + l) * 8) = r.q;   // 1KB/wave coalesced
    }
    part[w][l] = s;
    __syncthreads();
    if (w == 0) {
        float t = part[0][l] + part[1][l] + part[2][l] + part[3][l];
        chalf[c0 + l] = 0.5f * t + SHIFT;
    }
}

// ---------------------------------------------------------------- kernel 2
// Double-buffered hybrid GEMM+argmin. grid (64, 8), 4 waves; block =
// 256 rows x 64-code tiles (16 tiles/group). Wave = 64 rows x ALL 64 codes
// (rt=4, ct=4) -> no cross-wave key reduce. A panel in VGPRs (fp32 load +
// in-reg bf16 cvt). B double-buffered in LDS: per tile, ONE barrier drains
// the DMA issued one full compute phase earlier (round-6 structure exposed
// the DMA by draining right after issue); prefetch is issued AFTER the
// barrier so vmcnt(0) doesn't touch it.
__global__ __launch_bounds__(256, 2) void k_gemm_argmin(
    const float* __restrict__ xs,              // [M_TOK][DIM] fp32
    const unsigned short* __restrict__ cbt,    // [NCHK][KCB][8] bf16 of -c
    const float* __restrict__ chalf,           // [KCB] = 0.5||c||^2+SHIFT
    uint32_t* __restrict__ pkey)               // [M_TOK][NGRP]
{
    __shared__ __align__(16) unsigned short Bs[2][NCHK][64][8];   // 64 KB
    __shared__ float schalf[GRP];                                  // 4 KB

    const int tid  = threadIdx.x;
    const int w    = tid >> 6;
    const int l    = tid & 63;
    const int lrow = l & 15;
    const int quad = l >> 4;
    const int m0 = blockIdx.x * 256;
    const int g  = blockIdx.y;

    // chalf slice (4 KB) -> LDS
    *(float4*)&schalf[tid * 4] = ((const float4*)(chalf + g * GRP))[tid];

    // staging source: wave w supplies chunks [8w,8w+8); lane = code in tile
    const unsigned short* bsrc = cbt + ((size_t)(w * 8) * KCB + g * GRP + l) * 8;

    // prefetch tile 0 into buf 0
    #pragma unroll
    for (int j = 0; j < 8; j++)
        lds_cp16(bsrc + (size_t)j * KCB * 8, &Bs[0][w * 8 + j][0][0]);

    // ---- A panel: 64 rows x 256 k, fp32 -> bf16 frags (128 VGPRs)
    bf16x8 afr[4][8];
    {
        const float* ap = xs + (size_t)(m0 + w * 64 + lrow) * DIM + quad * 8;
        #pragma unroll
        for (int rt = 0; rt < 4; rt++)
            #pragma unroll
            for (int kt = 0; kt < 8; kt++) {
                const float* p = ap + rt * 16 * DIM + kt * 32;
                float4 f0 = *(const float4*)p;
                float4 f1 = *(const float4*)(p + 4);
                afr[rt][kt] = cvt8(f0, f1);
            }
    }

    uint32_t best[4][4];
    #pragma unroll
    for (int rt = 0; rt < 4; rt++)
        #pragma unroll
        for (int rg = 0; rg < 4; rg++) best[rt][rg] = 0xFFFFFFFFu;

    #pragma unroll 1
    for (int t = 0; t < NT; t++) {
        const int cur = t & 1;
        __syncthreads();   // drains DMA(t) — issued one compute phase ago
        if (t < NT - 1) {  // prefetch t+1 AFTER the barrier (not drained by it)
            #pragma unroll
            for (int j = 0; j < 8; j++)
                lds_cp16(bsrc + ((size_t)j * KCB + (t + 1) * 64) * 8,
                         &Bs[1 - cur][w * 8 + j][0][0]);
        }

        f32x4 acc[4][4];
        #pragma unroll
        for (int ct = 0; ct < 4; ct++) {
            float cs = schalf[t * 64 + ct * 16 + lrow];
            #pragma unroll
            for (int rt = 0; rt < 4; rt++) {
                f32x4 c4 = {cs, cs, cs, cs};
                acc[rt][ct] = c4;
            }
        }
        #pragma unroll
        for (int bk = 0; bk < 8; bk++) {
            bf16x8 bfr[4];
            #pragma unroll
            for (int ct = 0; ct < 4; ct++)
                bfr[ct] = *(const bf16x8*)&Bs[cur][bk * 4 + quad]
                                             [ct * 16 + lrow][0];
            #pragma unroll
            for (int rt = 0; rt < 4; rt++)
                #pragma unroll
                for (int ct = 0; ct < 4; ct++)
                    acc[rt][ct] = __builtin_amdgcn_mfma_f32_16x16x32_bf16(
                        afr[rt][bk], bfr[ct], acc[rt][ct], 0, 0, 0);
        }
        // fold scores into packed keys: (score_bits & ~1023) | group-local id
        #pragma unroll
        for (int ct = 0; ct < 4; ct++) {
            uint32_t idl = (uint32_t)(t * 64 + ct * 16 + lrow);
            #pragma unroll
            for (int rt = 0; rt < 4; rt++)
                #pragma unroll
                for (int rg = 0; rg < 4; rg++) {
                    uint32_t key =
                        (__float_as_uint(acc[rt][ct][rg]) & 0xFFFFFC00u) | idl;
                    if (key < best[rt][rg]) best[rt][rg] = key;
                }
        }
    }

    // min across the 16 lanes of each quad group (same rows, different codes)
    #pragma unroll
    for (int off = 1; off < 16; off <<= 1)
        #pragma unroll
        for (int rt = 0; rt < 4; rt++)
            #pragma unroll
            for (int rg = 0; rg < 4; rg++) {
                uint32_t o = __shfl_xor(best[rt][rg], off);
                if (o < best[rt][rg]) best[rt][rg] = o;
            }
    if (lrow == 0) {
        #pragma unroll
        for (int rt = 0; rt < 4; rt++)
            #pragma unroll
            for (int rg = 0; rg < 4; rg++)
                pkey[(size_t)(m0 + w * 64 + rt * 16 + quad * 4 + rg) * NGRP + g]
                    = best[rt][rg];
    }
}

// ---------------------------------------------------------------- kernel 3
// Per row: min over 8 group keys -> final code; exact fp32 ||x-c||^2;
// per-block LDS reduce -> partial[blockIdx]. No global atomics.
__global__ void k_finalize(const uint32_t* __restrict__ pkey,
                           const float4* __restrict__ xs4,
                           const float4* __restrict__ cb4,
                           float* __restrict__ partial) {
    __shared__ float sblk[4];
    int w   = threadIdx.x >> 6;
    int row = blockIdx.x * 4 + w;
    int l   = threadIdx.x & 63;
    uint32_t k = 0xFFFFFFFFu;
    int g = 0;
    if (l < 8) { k = pkey[(size_t)row * NGRP + l]; g = l; }
    #pragma unroll
    for (int off = 1; off < 8; off <<= 1) {
        uint32_t ok = __shfl_xor(k, off);
        int      og = __shfl_xor(g, off);
        if (ok < k) { k = ok; g = og; }
    }
    k = __shfl(k, 0);
    g = __shfl(g, 0);
    int code = g * GRP + (int)(k & 1023u);
    float4 x = xs4[(size_t)row * 64 + l];
    float4 c = cb4[(size_t)code * 64 + l];
    float dx = x.x - c.x, dy = x.y - c.y, dz = x.z - c.z, dw = x.w - c.w;
    float s = dx * dx + dy * dy + dz * dz + dw * dw;
    #pragma unroll
    for (int off = 32; off; off >>= 1) s += __shfl_xor(s, off);
    if (l == 0) sblk[w] = s;
    __syncthreads();
    if (threadIdx.x == 0)
        partial[blockIdx.x] = sblk[0] + sblk[1] + sblk[2] + sblk[3];
}

// ---------------------------------------------------------------- kernel 4
__global__ void k_write(const float* __restrict__ partial,
                        float* __restrict__ out) {
    __shared__ float swv[16];
    int tid = threadIdx.x;                    // 1024 threads = 16 waves
    float s = partial[tid] + partial[tid + 1024] +
              partial[tid + 2048] + partial[tid + 3072];
    #pragma unroll
    for (int off = 32; off; off >>= 1) s += __shfl_xor(s, off);
    if ((tid & 63) == 0) swv[tid >> 6] = s;
    __syncthreads();
    if (tid == 0) {
        float t = 0.0f;
        #pragma unroll
        for (int i = 0; i < 16; i++) t += swv[i];
        float commit = t * INV_N;
        out[0] = 0.25f * commit;   // loss
        out[1] = commit;           // commit_loss
    }
}

extern "C" void kernel_launch(void* const* d_in, const int* in_sizes, int n_in,
                              void* d_out, int out_size, void* d_ws, size_t ws_size,
                              hipStream_t stream) {
    const float* xs = (const float*)d_in[0];
    // d_in[1] = ilens (int64, all == T) -> slice is a no-op, unused
    const float* cb = (const float*)d_in[2];

    char* ws = (char*)d_ws;
    unsigned short* cbt     = (unsigned short*)(ws + 256);          // 4 MiB
    float*          chalf   = (float*)(ws + 256 + 4194304);         // 32 KiB
    uint32_t*       pkey    = (uint32_t*)(ws + 256 + 4227072);      // 512 KiB
    float*          partial = (float*)(ws + 256 + 4751360);         // 16 KiB

    k_prep<<<128, 256, 0, stream>>>(cb, cbt, chalf);
    dim3 g(M_TOK / 256, NGRP);
    k_gemm_argmin<<<g, 256, 0, stream>>>(xs, cbt, chalf, pkey);
    k_finalize<<<4096, 256, 0, stream>>>(pkey, (const float4*)xs,
                                         (const float4*)cb, partial);
    k_write<<<1, 1024, 0, stream>>>(partial, (float*)d_out);
}